// Round 2
// baseline (8037.157 us; speedup 1.0000x reference)
//
#include <hip/hip_runtime.h>
#include <hip/hip_bf16.h>

#define EPSF 1e-15f

// ---------- math helpers ----------
__device__ __forceinline__ float artanh_c(float x) {
  x = fminf(fmaxf(x, -1.f + 1e-5f), 1.f - 1e-5f);
  return 0.5f * log1pf(2.f * x / (1.f - x));   // accurate for tiny x
}
__device__ __forceinline__ float sigmoidf(float x) {
  return 1.f / (1.f + expf(-x));
}

// multi-value block reduction, blockDim.x == 256 (4 waves)
template<int N>
__device__ __forceinline__ void block_reduce(float* v) {
  __shared__ float s[4][N];
  __syncthreads();                       // protect reuse across calls
  const int lane = threadIdx.x & 63;
  const int wv = threadIdx.x >> 6;
#pragma unroll
  for (int n = 0; n < N; n++) {
    float x = v[n];
#pragma unroll
    for (int o = 32; o > 0; o >>= 1) x += __shfl_down(x, o);
    if (lane == 0) s[wv][n] = x;
  }
  __syncthreads();
#pragma unroll
  for (int n = 0; n < N; n++) v[n] = s[0][n] + s[1][n] + s[2][n] + s[3][n];
}

// ---------- token prologue: per (gru,b,s) expmap0 norm factors ----------
__global__ __launch_bounds__(256) void k_tok(
    const float* __restrict__ emb, const int* __restrict__ src_t,
    const int* __restrict__ tgt_t, float4* __restrict__ tokf)
{
  const int item = blockIdx.x * 4 + (threadIdx.x >> 6);  // 2*512*100 items
  const int lane = threadIdx.x & 63;
  const int g = item / 51200;
  const int rem = item - g * 51200;
  const int b = rem / 100, s = rem - b * 100;
  const int tok = (g ? tgt_t : src_t)[b * 100 + s];
  const float4 v = ((const float4*)(emb + (size_t)tok * 256))[lane];
  float ss = v.x*v.x + v.y*v.y + v.z*v.z + v.w*v.w;
#pragma unroll
  for (int o = 32; o > 0; o >>= 1) ss += __shfl_xor(ss, o);
  if (lane == 0) {
    const float un = sqrtf(fmaxf(ss, EPSF));
    const float fac = tanhf(un) / un;
    const float xn = sqrtf(fmaxf(fac * fac * ss, EPSF));
    const float axn = artanh_c(xn);
    tokf[item] = make_float4(fac, xn, axn, un);
  }
}

// ---------- fill xbuf for step 0 ----------
__global__ __launch_bounds__(256) void kx0(
    const float* __restrict__ emb, const int* __restrict__ src_t,
    const int* __restrict__ tgt_t, const float4* __restrict__ tokf,
    float* __restrict__ xb)
{
  const int row = blockIdx.x;            // 0..1023
  const int t = threadIdx.x;             // 0..255 == E
  const int g = row >> 9, b = row & 511;
  const int tok = (g ? tgt_t : src_t)[b * 100];
  const float fac = tokf[(g * 512 + b) * 100].x;
  xb[(size_t)row * 256 + t] = fac * emb[(size_t)tok * 256 + t];
}

// ---------- generic f32 GEMM: out[row, col] = sum_k A[row,k] * W[col,k] ----------
// mode 0: K1  rows=1024 (h|x), cols=2560 (Whz|Whr|Uxz|Uxr|Uxh per gru)
// mode 1: K3  rows=1024 (rh), cols=512 (W_hh_)
// mode 2: head rows=512, cols=512 (wp_src | wp_tgt with alignment gather)
__global__ __launch_bounds__(256) void gemm_k(
    int mode,
    const float* __restrict__ hbuf, const float* __restrict__ xbuf,
    const float* __restrict__ rhbuf,
    const float* __restrict__ w_ih_src, const float* __restrict__ w_hh_src,
    const float* __restrict__ w_ih_tgt, const float* __restrict__ w_hh_tgt,
    const float* __restrict__ wp_src, const float* __restrict__ wp_tgt,
    const int* __restrict__ alignment,
    float* __restrict__ out)
{
  const int rt = blockIdx.x, ct = blockIdx.y;
  const int rowBase = rt * 64;
  const int tid = threadIdx.x;
  int kdim, ldo, colBase;
  const float* W;
  const float* Abase;
  int gather = 0;
  if (mode == 0) {
    const int chunk = ct >> 3;
    colBase = ct * 64; ldo = 2560;
    const int g = rowBase >> 9;
    const float* wih = g ? w_ih_tgt : w_ih_src;
    const float* whh = g ? w_hh_tgt : w_hh_src;
    if (chunk == 0)      { W = whh + 2 * 512 * 512; Abase = hbuf; kdim = 512; }
    else if (chunk == 1) { W = whh;                 Abase = hbuf; kdim = 512; }
    else {
      kdim = 256; Abase = xbuf;
      W = (chunk == 2) ? (wih + 2 * 512 * 256) : ((chunk == 3) ? wih : (wih + 512 * 256));
    }
    W += (size_t)((ct & 7) * 64) * kdim;
  } else if (mode == 1) {
    const int g = rowBase >> 9;
    W = (g ? w_hh_tgt : w_hh_src) + 512 * 512 + (size_t)(ct * 64) * 512;
    Abase = rhbuf; kdim = 512; ldo = 512; colBase = ct * 64;
  } else {
    const int chunk = ct >> 2;
    colBase = ct * 64; ldo = 512; kdim = 512;
    W = (chunk ? wp_tgt : wp_src) + (size_t)((ct & 3) * 64) * 512;
    Abase = hbuf;
    gather = chunk;
  }
  const int ar = tid >> 2, ak = (tid & 3) * 4;
  int arow = rowBase + ar;
  if (mode == 2 && gather) arow = 512 + alignment[arow];
  const float* Arow = Abase + (size_t)arow * kdim;     // lda == kdim everywhere
  const float* Wrow = W + (size_t)(tid >> 2) * kdim + (tid & 3) * 4;

  __shared__ __align__(16) float As[16][68];
  __shared__ __align__(16) float Bs[16][68];
  float acc[4][4] = {{0.f}};
  const int ty = tid >> 4, tx = tid & 15;

  for (int k0 = 0; k0 < kdim; k0 += 16) {
    const float4 av = *(const float4*)(Arow + k0 + ak);
    const float4 bv = *(const float4*)(Wrow + k0);
    const int bj = tid >> 2;
    As[ak + 0][ar] = av.x; As[ak + 1][ar] = av.y; As[ak + 2][ar] = av.z; As[ak + 3][ar] = av.w;
    Bs[ak + 0][bj] = bv.x; Bs[ak + 1][bj] = bv.y; Bs[ak + 2][bj] = bv.z; Bs[ak + 3][bj] = bv.w;
    __syncthreads();
#pragma unroll
    for (int kk = 0; kk < 16; kk++) {
      const float4 a4 = *(const float4*)(&As[kk][ty * 4]);
      const float4 b4 = *(const float4*)(&Bs[kk][tx * 4]);
      acc[0][0] += a4.x * b4.x; acc[0][1] += a4.x * b4.y; acc[0][2] += a4.x * b4.z; acc[0][3] += a4.x * b4.w;
      acc[1][0] += a4.y * b4.x; acc[1][1] += a4.y * b4.y; acc[1][2] += a4.y * b4.z; acc[1][3] += a4.y * b4.w;
      acc[2][0] += a4.z * b4.x; acc[2][1] += a4.z * b4.y; acc[2][2] += a4.z * b4.z; acc[2][3] += a4.z * b4.w;
      acc[3][0] += a4.w * b4.x; acc[3][1] += a4.w * b4.y; acc[3][2] += a4.w * b4.z; acc[3][3] += a4.w * b4.w;
    }
    __syncthreads();
  }
#pragma unroll
  for (int r = 0; r < 4; r++) {
    float4 o; o.x = acc[r][0]; o.y = acc[r][1]; o.z = acc[r][2]; o.w = acc[r][3];
    *(float4*)(out + (size_t)(rowBase + ty * 4 + r) * ldo + colBase + tx * 4) = o;
  }
}

// ---------- K2: gates z, r ; rh ; scaled Ux_h ----------
__global__ __launch_bounds__(256) void k2_gates(
    const float* __restrict__ g1, const float* __restrict__ hb,
    const float* __restrict__ b_src, const float* __restrict__ b_tgt,
    const float4* __restrict__ tokf,
    float* __restrict__ zb, float* __restrict__ rhb,
    float* __restrict__ uhxb, float* __restrict__ rn, int s)
{
  const int row = blockIdx.x;
  const int g = row >> 9, b = row & 511;
  const int t = threadIdx.x;
  const float* bb = g ? b_tgt : b_src;
  const float4 tf = tokf[(g * 512 + b) * 100 + s];
  const float xn_x = tf.y, axn_x = tf.z;
  const float* grow = g1 + (size_t)row * 2560;
  const float* hrow = hb + (size_t)row * 512;

  float h[2], whz[2], whr[2], uxz[2], uxr[2], uxh[2], bz[2], br[2];
  float r6[6] = {0, 0, 0, 0, 0, 0};
#pragma unroll
  for (int e = 0; e < 2; e++) {
    const int j = t + e * 256;
    h[e] = hrow[j];
    whz[e] = grow[j];        whr[e] = grow[512 + j];
    uxz[e] = grow[1024 + j]; uxr[e] = grow[1536 + j];
    uxh[e] = grow[2048 + j];
    bz[e] = bb[1024 + j];    br[e] = bb[j];
    r6[0] += h[e] * h[e];     r6[1] += whz[e] * whz[e]; r6[2] += whr[e] * whr[e];
    r6[3] += uxz[e] * uxz[e]; r6[4] += uxr[e] * uxr[e]; r6[5] += uxh[e] * uxh[e];
  }
  block_reduce<6>(r6);
  const float sh2 = r6[0];
  const float xn_h = sqrtf(fmaxf(sh2, EPSF)), axn_h = artanh_c(xn_h);

  const float mz = sqrtf(fmaxf(r6[1], EPSF)); const float tz = tanhf(mz / xn_h * axn_h);
  const float sz = (mz <= 1e-7f) ? 0.f : tz / mz; const float x2z = (mz <= 1e-7f) ? 0.f : tz * tz;
  const float mr = sqrtf(fmaxf(r6[2], EPSF)); const float tr = tanhf(mr / xn_h * axn_h);
  const float sr = (mr <= 1e-7f) ? 0.f : tr / mr; const float x2r = (mr <= 1e-7f) ? 0.f : tr * tr;
  const float muz = sqrtf(fmaxf(r6[3], EPSF)); const float tuz = tanhf(muz / xn_x * axn_x);
  const float suz = (muz <= 1e-7f) ? 0.f : tuz / muz; const float y2z = (muz <= 1e-7f) ? 0.f : tuz * tuz;
  const float mur = sqrtf(fmaxf(r6[4], EPSF)); const float tur = tanhf(mur / xn_x * axn_x);
  const float sur = (mur <= 1e-7f) ? 0.f : tur / mur; const float y2r = (mur <= 1e-7f) ? 0.f : tur * tur;
  const float muh = sqrtf(fmaxf(r6[5], EPSF)); const float tuh = tanhf(muh / xn_x * axn_x);
  const float suh = (muh <= 1e-7f) ? 0.f : tuh / muh; const float y2u = (muh <= 1e-7f) ? 0.f : tuh * tuh;

  float Wz[2], Uz[2], Wr[2], Ur[2];
  float dd[2] = {0, 0};
#pragma unroll
  for (int e = 0; e < 2; e++) {
    Wz[e] = sz * whz[e]; Uz[e] = suz * uxz[e];
    Wr[e] = sr * whr[e]; Ur[e] = sur * uxr[e];
    dd[0] += Wz[e] * Uz[e]; dd[1] += Wr[e] * Ur[e];
  }
  block_reduce<2>(dd);
  float t1z[2], t1r[2];
  {
    const float xy = dd[0];
    const float iv = 1.f / fmaxf(1.f + 2.f * xy + x2z * y2z, EPSF);
    const float c1 = 1.f + 2.f * xy + y2z, c2 = 1.f - x2z;
#pragma unroll
    for (int e = 0; e < 2; e++) t1z[e] = (c1 * Wz[e] + c2 * Uz[e]) * iv;
  }
  {
    const float xy = dd[1];
    const float iv = 1.f / fmaxf(1.f + 2.f * xy + x2r * y2r, EPSF);
    const float c1 = 1.f + 2.f * xy + y2r, c2 = 1.f - x2r;
#pragma unroll
    for (int e = 0; e < 2; e++) t1r[e] = (c1 * Wr[e] + c2 * Ur[e]) * iv;
  }
  float r6b[6] = {0, 0, 0, 0, 0, 0};
#pragma unroll
  for (int e = 0; e < 2; e++) {
    r6b[0] += t1z[e] * t1z[e]; r6b[1] += t1z[e] * bz[e]; r6b[2] += bz[e] * bz[e];
    r6b[3] += t1r[e] * t1r[e]; r6b[4] += t1r[e] * br[e]; r6b[5] += br[e] * br[e];
  }
  block_reduce<6>(r6b);
  float t2z[2], t2r[2];
  {
    const float x2 = r6b[0], xy = r6b[1], y2 = r6b[2];
    const float iv = 1.f / fmaxf(1.f + 2.f * xy + x2 * y2, EPSF);
    const float c1 = 1.f + 2.f * xy + y2, c2 = 1.f - x2;
#pragma unroll
    for (int e = 0; e < 2; e++) t2z[e] = (c1 * t1z[e] + c2 * bz[e]) * iv;
  }
  {
    const float x2 = r6b[3], xy = r6b[4], y2 = r6b[5];
    const float iv = 1.f / fmaxf(1.f + 2.f * xy + x2 * y2, EPSF);
    const float c1 = 1.f + 2.f * xy + y2, c2 = 1.f - x2;
#pragma unroll
    for (int e = 0; e < 2; e++) t2r[e] = (c1 * t1r[e] + c2 * br[e]) * iv;
  }
  float nn[2] = {0, 0};
#pragma unroll
  for (int e = 0; e < 2; e++) { nn[0] += t2z[e] * t2z[e]; nn[1] += t2r[e] * t2r[e]; }
  block_reduce<2>(nn);
  const float nz = sqrtf(fmaxf(nn[0], EPSF)); const float fz = artanh_c(nz) / nz;
  const float nr = sqrtf(fmaxf(nn[1], EPSF)); const float fr = artanh_c(nr) / nr;
  float zz[2], wx[2];
  float rw[1] = {0};
#pragma unroll
  for (int e = 0; e < 2; e++) {
    zz[e] = sigmoidf(fz * t2z[e]);
    const float rr = sigmoidf(fr * t2r[e]);
    wx[e] = rr * h[e];
    rw[0] += wx[e] * wx[e];
  }
  block_reduce<1>(rw);
  const float wxn = sqrtf(fmaxf(rw[0], EPSF));
  const float trh = tanhf(wxn / xn_h * axn_h);
  const float srh = (wxn <= 1e-7f) ? 0.f : trh / wxn;
  const float xn_rh = (wxn <= 1e-7f) ? sqrtf(EPSF) : fmaxf(trh, sqrtf(EPSF));
  const float axn_rh = artanh_c(xn_rh);
#pragma unroll
  for (int e = 0; e < 2; e++) {
    const int j = t + e * 256;
    zb[(size_t)row * 512 + j] = zz[e];
    rhb[(size_t)row * 512 + j] = srh * wx[e];
    uhxb[(size_t)row * 512 + j] = suh * uxh[e];
  }
  if (t == 0) {
    float* r8 = rn + row * 8;
    r8[0] = xn_h; r8[1] = axn_h; r8[2] = xn_rh; r8[3] = axn_rh; r8[4] = y2u; r8[5] = sh2;
  }
}

// ---------- K4: h_tilde, delta, h_new ; prefetch next x ----------
__global__ __launch_bounds__(256) void k4_update(
    const float* __restrict__ htm, const float* __restrict__ uhxb,
    const float* __restrict__ zb, float* __restrict__ hb,
    const float* __restrict__ b_src, const float* __restrict__ b_tgt,
    const float* __restrict__ rn, const float4* __restrict__ tokf,
    const int* __restrict__ src_t, const int* __restrict__ tgt_t,
    const float* __restrict__ emb, float* __restrict__ xb, int s)
{
  const int row = blockIdx.x;
  const int g = row >> 9, b = row & 511;
  const int t = threadIdx.x;
  const float* bb = g ? b_tgt : b_src;
  const float* r8 = rn + row * 8;
  const float xn_rh = r8[2], axn_rh = r8[3], y2u = r8[4], sh2 = r8[5];

  float mt_[2], ux[2], z[2], h[2], bh[2];
  float rA[2] = {0, 0};
#pragma unroll
  for (int e = 0; e < 2; e++) {
    const int j = t + e * 256;
    mt_[e] = htm[(size_t)row * 512 + j];
    ux[e] = uhxb[(size_t)row * 512 + j];
    z[e] = zb[(size_t)row * 512 + j];
    h[e] = hb[(size_t)row * 512 + j];
    bh[e] = bb[512 + j];
    rA[0] += mt_[e] * mt_[e];
    rA[1] += mt_[e] * ux[e];
  }
  block_reduce<2>(rA);
  const float m = sqrtf(fmaxf(rA[0], EPSF));
  const float tt = tanhf(m / xn_rh * axn_rh);
  const float st = (m <= 1e-7f) ? 0.f : tt / m;
  const float x2 = (m <= 1e-7f) ? 0.f : tt * tt;
  float t1[2];
  {
    const float xy = st * rA[1];
    const float iv = 1.f / fmaxf(1.f + 2.f * xy + x2 * y2u, EPSF);
    const float c1 = 1.f + 2.f * xy + y2u, c2 = 1.f - x2;
#pragma unroll
    for (int e = 0; e < 2; e++) t1[e] = (c1 * (st * mt_[e]) + c2 * ux[e]) * iv;
  }
  float rB[3] = {0, 0, 0};
#pragma unroll
  for (int e = 0; e < 2; e++) {
    rB[0] += t1[e] * t1[e]; rB[1] += t1[e] * bh[e]; rB[2] += bh[e] * bh[e];
  }
  block_reduce<3>(rB);
  float ht[2];
  {
    const float x2b = rB[0], xy = rB[1], y2 = rB[2];
    const float iv = 1.f / fmaxf(1.f + 2.f * xy + x2b * y2, EPSF);
    const float c1 = 1.f + 2.f * xy + y2, c2 = 1.f - x2b;
#pragma unroll
    for (int e = 0; e < 2; e++) ht[e] = (c1 * t1[e] + c2 * bh[e]) * iv;
  }
  float rC[2] = {0, 0};
#pragma unroll
  for (int e = 0; e < 2; e++) { rC[0] += ht[e] * ht[e]; rC[1] += h[e] * ht[e]; }
  block_reduce<2>(rC);
  float delta[2];
  {
    const float y2 = rC[0], xy = -rC[1];
    const float iv = 1.f / fmaxf(1.f + 2.f * xy + sh2 * y2, EPSF);
    const float c1 = 1.f + 2.f * xy + y2, c2 = 1.f - sh2;
#pragma unroll
    for (int e = 0; e < 2; e++) delta[e] = (c1 * (-h[e]) + c2 * ht[e]) * iv;
  }
  float rD[3] = {0, 0, 0};
#pragma unroll
  for (int e = 0; e < 2; e++) {
    const float w = z[e] * delta[e];
    rD[0] += delta[e] * delta[e];
    rD[1] += w * w;
    rD[2] += h[e] * w;
  }
  block_reduce<3>(rD);
  const float dn = sqrtf(fmaxf(rD[0], EPSF));
  const float axnd = artanh_c(dn);
  const float wxn = sqrtf(fmaxf(rD[1], EPSF));
  const float tzd = tanhf(wxn / dn * axnd);
  const float szd = (wxn <= 1e-7f) ? 0.f : tzd / wxn;
  const float y2zd = (wxn <= 1e-7f) ? 0.f : tzd * tzd;
  {
    const float xy = szd * rD[2];
    const float iv = 1.f / fmaxf(1.f + 2.f * xy + sh2 * y2zd, EPSF);
    const float c1 = 1.f + 2.f * xy + y2zd, c2 = 1.f - sh2;
#pragma unroll
    for (int e = 0; e < 2; e++) {
      const int j = t + e * 256;
      hb[(size_t)row * 512 + j] = (c1 * h[e] + c2 * (szd * z[e] * delta[e])) * iv;
    }
  }
  if (s + 1 < 100) {
    const int tok = (g ? tgt_t : src_t)[b * 100 + s + 1];
    const float fac = tokf[(g * 512 + b) * 100 + s + 1].x;
    xb[(size_t)row * 256 + t] = fac * emb[(size_t)tok * 256 + t];
  }
}

// ---------- head: mobius_linear x2, mobius_add, dist, scalar_mul, dist2plane ----------
__global__ __launch_bounds__(256) void k_head(
    const float* __restrict__ hb, const float* __restrict__ mxb,
    const float* __restrict__ bp_src, const float* __restrict__ bp_tgt,
    const float* __restrict__ dist_bias, const float* __restrict__ plane_p,
    const float* __restrict__ plane_a, const int* __restrict__ alignment,
    float* __restrict__ outp)
{
  const int b = blockIdx.x;
  const int t = threadIdx.x;
  const int arow = 512 + alignment[b];
  float hs[2], htg[2];
  hs[0] = hb[(size_t)b * 512 + t];      hs[1] = hb[(size_t)b * 512 + 256 + t];
  htg[0] = hb[(size_t)arow * 512 + t];  htg[1] = hb[(size_t)arow * 512 + 256 + t];
  const float mxs = mxb[(size_t)b * 512 + t];
  const float mxt = mxb[(size_t)b * 512 + 256 + t];
  const float bps = bp_src[t], bpt = bp_tgt[t], db = dist_bias[t];
  const float pp0 = plane_p[t], pp1 = plane_p[256 + t];
  const float pa0 = plane_a[t], pa1 = plane_a[256 + t];

  float rA[5] = {0, 0, 0, 0, 0};
#pragma unroll
  for (int e = 0; e < 2; e++) {
    rA[0] += hs[e] * hs[e]; rA[1] += htg[e] * htg[e]; rA[2] += hs[e] * htg[e];
  }
  rA[3] = mxs * mxs; rA[4] = mxt * mxt;
  block_reduce<5>(rA);
  const float shs = rA[0], sht = rA[1], dot_st = rA[2];
  const float xns = sqrtf(fmaxf(shs, EPSF)), axns = artanh_c(xns);
  const float xnt = sqrtf(fmaxf(sht, EPSF)), axnt = artanh_c(xnt);
  const float ms = sqrtf(fmaxf(rA[3], EPSF)); const float ts = tanhf(ms / xns * axns);
  const float ss = (ms <= 1e-7f) ? 0.f : ts / ms; const float x2s = (ms <= 1e-7f) ? 0.f : ts * ts;
  const float mt = sqrtf(fmaxf(rA[4], EPSF)); const float tt = tanhf(mt / xnt * axnt);
  const float st = (mt <= 1e-7f) ? 0.f : tt / mt; const float x2t = (mt <= 1e-7f) ? 0.f : tt * tt;
  const float vs = ss * mxs, vt = st * mxt;

  float rB[5] = {bps * bps, vs * bps, bpt * bpt, vt * bpt, db * db};
  block_reduce<5>(rB);
  float ps, pt;
  {
    const float y2 = rB[0], xy = rB[1];
    const float iv = 1.f / fmaxf(1.f + 2.f * xy + x2s * y2, EPSF);
    ps = ((1.f + 2.f * xy + y2) * vs + (1.f - x2s) * bps) * iv;
  }
  {
    const float y2 = rB[2], xy = rB[3];
    const float iv = 1.f / fmaxf(1.f + 2.f * xy + x2t * y2, EPSF);
    pt = ((1.f + 2.f * xy + y2) * vt + (1.f - x2t) * bpt) * iv;
  }
  float rC[2] = {ps * ps, pt * pt};
  block_reduce<2>(rC);
  {
    const float n = sqrtf(fmaxf(rC[0], EPSF));
    if (n > 0.999f) ps *= 0.999f / n;
  }
  {
    const float n = sqrtf(fmaxf(rC[1], EPSF));
    if (n > 0.999f) pt *= 0.999f / n;
  }
  // d2 diff over H
  float df[2];
  {
    const float xy = -dot_st;
    const float iv = 1.f / fmaxf(1.f + 2.f * xy + shs * sht, EPSF);
    const float c1 = 1.f + 2.f * xy + sht, c2 = 1.f - shs;
#pragma unroll
    for (int e = 0; e < 2; e++) df[e] = (c1 * (-hs[e]) + c2 * htg[e]) * iv;
  }
  float rD[4] = {ps * ps, pt * pt, ps * pt, df[0] * df[0] + df[1] * df[1]};
  block_reduce<4>(rD);
  float pr;
  {
    const float x2 = rD[0], y2 = rD[1], xy = rD[2];
    const float iv = 1.f / fmaxf(1.f + 2.f * xy + x2 * y2, EPSF);
    pr = ((1.f + 2.f * xy + y2) * ps + (1.f - x2) * pt) * iv;
  }
  const float dn = sqrtf(fmaxf(rD[3], EPSF));
  const float dist = 2.f * artanh_c(dn);
  const float d2v = dist * dist;
  const float dbn = sqrtf(fmaxf(rB[4], EPSF));
  const float biasv = tanhf(d2v * artanh_c(dbn)) * db / dbn;

  float rE[3] = {pr * pr, biasv * biasv, pr * biasv};
  block_reduce<3>(rE);
  float pr2;
  {
    const float x2 = rE[0], y2 = rE[1], xy = rE[2];
    const float iv = 1.f / fmaxf(1.f + 2.f * xy + x2 * y2, EPSF);
    pr2 = ((1.f + 2.f * xy + y2) * pr + (1.f - x2) * biasv) * iv;
  }
  float rF[5] = {pp0 * pp0, pp0 * pr2, pp1 * pp1, pp1 * pr2, pr2 * pr2};
  block_reduce<5>(rF);
  float d0, d1;
  {
    const float x2 = rF[0], xy = -rF[1], y2 = rF[4];
    const float iv = 1.f / fmaxf(1.f + 2.f * xy + x2 * y2, EPSF);
    d0 = ((1.f + 2.f * xy + y2) * (-pp0) + (1.f - x2) * pr2) * iv;
  }
  {
    const float x2 = rF[2], xy = -rF[3], y2 = rF[4];
    const float iv = 1.f / fmaxf(1.f + 2.f * xy + x2 * y2, EPSF);
    d1 = ((1.f + 2.f * xy + y2) * (-pp1) + (1.f - x2) * pr2) * iv;
  }
  float rG[6] = {d0 * d0, d0 * pa0, pa0 * pa0, d1 * d1, d1 * pa1, pa1 * pa1};
  block_reduce<6>(rG);
  if (t == 0) {
    const float an0 = sqrtf(fmaxf(rG[2], EPSF));
    const float an1 = sqrtf(fmaxf(rG[5], EPSF));
    const float l0 = asinhf(2.f * rG[1] / fmaxf((1.f - rG[0]) * an0, EPSF));
    const float l1 = asinhf(2.f * rG[4] / fmaxf((1.f - rG[3]) * an1, EPSF));
    outp[b * 2 + 0] = l0;   // float32 output (npz size evidence: 4033 B ≈ compressed 512x2 f32)
    outp[b * 2 + 1] = l1;
  }
}

// ---------- launch ----------
extern "C" void kernel_launch(void* const* d_in, const int* in_sizes, int n_in,
                              void* d_out, int out_size, void* d_ws, size_t ws_size,
                              hipStream_t stream) {
  const float* emb       = (const float*)d_in[0];
  const float* w_ih_src  = (const float*)d_in[1];
  const float* w_hh_src  = (const float*)d_in[2];
  const float* b_src     = (const float*)d_in[3];
  const float* w_ih_tgt  = (const float*)d_in[4];
  const float* w_hh_tgt  = (const float*)d_in[5];
  const float* b_tgt     = (const float*)d_in[6];
  const float* wp_src    = (const float*)d_in[7];
  const float* bp_src    = (const float*)d_in[8];
  const float* wp_tgt    = (const float*)d_in[9];
  const float* bp_tgt    = (const float*)d_in[10];
  const float* dist_bias = (const float*)d_in[11];
  const float* plane_p   = (const float*)d_in[12];
  const float* plane_a   = (const float*)d_in[13];
  const int* src_t       = (const int*)d_in[14];
  const int* tgt_t       = (const int*)d_in[15];
  const int* alignment   = (const int*)d_in[16];
  float* outp            = (float*)d_out;

  float* ws = (float*)d_ws;
  float* hbuf = ws + 0;                   // 1024*512
  float* xbuf = ws + 524288;              // 1024*256
  float* g1   = ws + 786432;              // 1024*2560
  float* zb   = ws + 3407872;             // 1024*512
  float* rhb  = ws + 3932160;             // 1024*512
  float* uhxb = ws + 4456448;             // 1024*512
  float* htm  = ws + 4980736;             // 1024*512
  float* rn   = ws + 5505024;             // 1024*8
  float4* tokf = (float4*)(ws + 5513216); // 2*512*100 float4
  float* mxb  = ws + 5922816;             // 512*512   (total ~24.7 MB)

  hipMemsetAsync(hbuf, 0, 1024 * 512 * sizeof(float), stream);
  k_tok<<<25600, 256, 0, stream>>>(emb, src_t, tgt_t, tokf);
  kx0<<<1024, 256, 0, stream>>>(emb, src_t, tgt_t, tokf, xbuf);
  for (int s = 0; s < 100; s++) {
    gemm_k<<<dim3(16, 40), 256, 0, stream>>>(0, hbuf, xbuf, rhb,
        w_ih_src, w_hh_src, w_ih_tgt, w_hh_tgt, wp_src, wp_tgt, alignment, g1);
    k2_gates<<<1024, 256, 0, stream>>>(g1, hbuf, b_src, b_tgt, tokf, zb, rhb, uhxb, rn, s);
    gemm_k<<<dim3(16, 8), 256, 0, stream>>>(1, hbuf, xbuf, rhb,
        w_ih_src, w_hh_src, w_ih_tgt, w_hh_tgt, wp_src, wp_tgt, alignment, htm);
    k4_update<<<1024, 256, 0, stream>>>(htm, uhxb, zb, hbuf, b_src, b_tgt, rn, tokf,
        src_t, tgt_t, emb, xbuf, s);
  }
  gemm_k<<<dim3(8, 8), 256, 0, stream>>>(2, hbuf, xbuf, rhb,
      w_ih_src, w_hh_src, w_ih_tgt, w_hh_tgt, wp_src, wp_tgt, alignment, mxb);
  k_head<<<512, 256, 0, stream>>>(hbuf, mxb, bp_src, bp_tgt, dist_bias,
      plane_p, plane_a, alignment, outp);
}